// Round 3
// baseline (1999.023 us; speedup 1.0000x reference)
//
#include <hip/hip_runtime.h>
#include <hip/hip_bf16.h>
#include <stdint.h>

typedef __hip_bfloat16 bf16_t;
typedef __attribute__((ext_vector_type(8))) short short8;
typedef __attribute__((ext_vector_type(4))) float f32x4;

#define MFMA16(a, b, c) __builtin_amdgcn_mfma_f32_16x16x32_bf16(a, b, c, 0, 0, 0)

#define NROW 50176   // B*S*S
#define NBATCH 1792  // B*S

__device__ __forceinline__ float sigm(float x) { return 1.0f / (1.0f + __expf(-x)); }
__device__ __forceinline__ float tanh_(float x) { return 2.0f / (1.0f + __expf(-2.0f * x)) - 1.0f; }
__device__ __forceinline__ void stc(bf16_t* p, float v) { *p = __float2bfloat16(v); }
__device__ __forceinline__ void stc(float* p, float v) { *p = v; }

// ---- fp32 -> bf16 weight conversion
__global__ void cvt_f2b(const float* __restrict__ src, bf16_t* __restrict__ dst, int n) {
  int i = blockIdx.x * 256 + threadIdx.x;
  if (i < n) dst[i] = __float2bfloat16(src[i]);
}

// ---- K0a: x fp32 [B,512,28,28] -> Xin [(b,h,w), 512] bf16
__global__ void transpose_x(const float* __restrict__ x, bf16_t* __restrict__ Xin) {
  int c0 = blockIdx.x * 128, h = blockIdx.y, b = blockIdx.z;
  __shared__ __align__(16) short tile[128 * 29];
  const float* xb = x + ((size_t)b * 512 + c0) * 784 + h * 28;
  for (int e = threadIdx.x; e < 128 * 28; e += 256) {
    int cc = e / 28, w = e - cc * 28;
    tile[cc * 29 + w] = __bfloat16_as_short(__float2bfloat16(xb[(size_t)cc * 784 + w]));
  }
  __syncthreads();
  short* outb = (short*)Xin + ((size_t)(b * 28 + h) * 28) * 512 + c0;
  for (int e = threadIdx.x; e < 28 * 128; e += 256) {
    int w = e >> 7, cc = e & 127;
    outb[(size_t)w * 512 + cc] = tile[cc * 29 + w];
  }
}

// ---- K0b: x_s[b][c][k<128] = x[b][c][3kh][3kw] (k<100), 0 pad (k>=100), bf16
__global__ void build_xs(const float* __restrict__ x, bf16_t* __restrict__ xs) {
  int c = blockIdx.x, b = blockIdx.y;
  int k = threadIdx.x;  // 128
  const float* xr = x + ((size_t)b * 512 + c) * 784;
  float v = 0.0f;
  if (k < 100) { int kh = k / 10, kw = k - kh * 10; v = xr[kh * 84 + kw * 3]; }
  xs[((size_t)b * 512 + c) * 128 + k] = __float2bfloat16(v);
}

// ---- K0c: pad conv_w fp32 [100,512] -> bf16 [128,512]; conv_b fp32 [100] -> fp32 [128]
__global__ void pad_conv(const float* __restrict__ cw, const float* __restrict__ cb,
                         bf16_t* __restrict__ cwp, float* __restrict__ cbp) {
  int r = blockIdx.x;  // 128
  for (int i = threadIdx.x; i < 512; i += 128)
    cwp[r * 512 + i] = __float2bfloat16((r < 100) ? cw[r * 512 + i] : 0.0f);
  if (r == 0) cbp[threadIdx.x] = (threadIdx.x < 100) ? cb[threadIdx.x] : 0.0f;
}

// ---- K1: C[M,N] = A[M,K] @ Bsel[N,K]^T + bias (A,B bf16; bias fp32; C bf16 or fp32)
template <typename CT>
__global__ __launch_bounds__(256) void gemm_bt(
    const bf16_t* __restrict__ A, const bf16_t* __restrict__ B0,
    const bf16_t* __restrict__ B1, int nsplit, const float* __restrict__ bias0,
    const float* __restrict__ bias1, CT* __restrict__ C, int M, int N, int K) {
  __shared__ __align__(16) short As[128 * 32];
  __shared__ __align__(16) short Bs[128 * 32];
  int tid = threadIdx.x;
  int bm0 = blockIdx.x * 128, bn0 = blockIdx.y * 128;
  const bf16_t* Bp;
  const float* biasp;
  if (bn0 < nsplit) { Bp = B0 + (size_t)bn0 * K; biasp = bias0 + bn0; }
  else { Bp = B1 + (size_t)(bn0 - nsplit) * K; biasp = bias1 + (bn0 - nsplit); }
  int lrow = tid >> 2, lseg = tid & 3;  // 4 threads x 16B cover one 32-elem row
  const char* Ag = (const char*)(A + (size_t)(bm0 + lrow) * K) + lseg * 16;
  const char* Bg = (const char*)(Bp + (size_t)lrow * K) + lseg * 16;
  size_t radv = (size_t)64 * K * 2;  // 64 rows down
  int w = tid >> 6, l = tid & 63, lm = l & 15, lq = l >> 4;
  int wm = w & 1, wn = w >> 1;
  f32x4 acc[4][4] = {};
  for (int k0 = 0; k0 < K; k0 += 32) {
    short8 a0 = *(const short8*)Ag;
    short8 a1 = *(const short8*)(Ag + radv);
    short8 b0 = *(const short8*)Bg;
    short8 b1 = *(const short8*)(Bg + radv);
    Ag += 64; Bg += 64;
    *(short8*)&As[lrow * 32 + lseg * 8] = a0;
    *(short8*)&As[(64 + lrow) * 32 + lseg * 8] = a1;
    *(short8*)&Bs[lrow * 32 + lseg * 8] = b0;
    *(short8*)&Bs[(64 + lrow) * 32 + lseg * 8] = b1;
    __syncthreads();
    short8 afr[4], bfr[4];
#pragma unroll
    for (int i = 0; i < 4; i++) {
      afr[i] = *(const short8*)&As[(wm * 64 + i * 16 + lm) * 32 + lq * 8];
      bfr[i] = *(const short8*)&Bs[(wn * 64 + i * 16 + lm) * 32 + lq * 8];
    }
#pragma unroll
    for (int mi = 0; mi < 4; mi++)
#pragma unroll
      for (int ni = 0; ni < 4; ni++) acc[mi][ni] = MFMA16(afr[mi], bfr[ni], acc[mi][ni]);
    __syncthreads();
  }
  float bv[4];
#pragma unroll
  for (int ni = 0; ni < 4; ni++) bv[ni] = biasp[wn * 64 + ni * 16 + lm];
#pragma unroll
  for (int mi = 0; mi < 4; mi++)
#pragma unroll
    for (int ni = 0; ni < 4; ni++) {
      int col = bn0 + wn * 64 + ni * 16 + lm;
#pragma unroll
      for (int r = 0; r < 4; r++) {
        size_t row = bm0 + wm * 64 + mi * 16 + lq * 4 + r;
        stc(&C[row * N + col], acc[mi][ni][r] + bv[ni]);
      }
    }
}

// ---- K2: one LSTM step, both directions. Wave w owns hidden slice j in [w*64,w*64+64)
// for ALL 4 gates -> i,f,g,o for (row,j) are in the same lane (no cross-wave epilogue).
__global__ __launch_bounds__(256) void lstm_step(
    const bf16_t* __restrict__ G, const bf16_t* __restrict__ whh_f,
    const bf16_t* __restrict__ whh_b, bf16_t* __restrict__ hstate,
    float* __restrict__ cstate, bf16_t* __restrict__ outb, int s) {
  int dir = blockIdx.y;
  int t = dir ? 27 - s : s;
  int r0 = blockIdx.x * 16;
  int tid = threadIdx.x, w = tid >> 6, l = tid & 63, lm = l & 15, lq = l >> 4;
  const short* whh = (const short*)(dir ? whh_b : whh_f);
  bf16_t* hs = hstate + (size_t)dir * NBATCH * 256;
  float* cs = cstate + (size_t)dir * NBATCH * 256;
  __shared__ __align__(16) short Ah[16 * 264];  // 16 rows x 256 + 8 pad
  f32x4 acc[4][4] = {};
  if (s > 0) {
    int row = tid >> 4, seg = tid & 15;
    const short* src = (const short*)hs + (size_t)(r0 + row) * 256 + seg * 16;
    short* dst = &Ah[row * 264 + seg * 16];
    *(short8*)dst = *(const short8*)src;
    *(short8*)(dst + 8) = *(const short8*)(src + 8);
    __syncthreads();
#pragma unroll
    for (int kk = 0; kk < 8; kk++) {
      short8 a = *(const short8*)&Ah[lm * 264 + kk * 32 + lq * 8];
#pragma unroll
      for (int gate = 0; gate < 4; gate++)
#pragma unroll
        for (int nj = 0; nj < 4; nj++) {
          int n = gate * 256 + w * 64 + nj * 16 + lm;
          short8 b = *(const short8*)&whh[(size_t)n * 256 + kk * 32 + lq * 8];
          acc[gate][nj] = MFMA16(a, b, acc[gate][nj]);
        }
    }
  }
#pragma unroll
  for (int nj = 0; nj < 4; nj++) {
    int j = w * 64 + nj * 16 + lm;
#pragma unroll
    for (int r = 0; r < 4; r++) {
      int bi = r0 + lq * 4 + r;
      size_t grow = ((size_t)bi * 28 + t) * 2048 + (size_t)dir * 1024;
      float gi = __bfloat162float(G[grow + 0 * 256 + j]) + acc[0][nj][r];
      float gf = __bfloat162float(G[grow + 1 * 256 + j]) + acc[1][nj][r];
      float gg = __bfloat162float(G[grow + 2 * 256 + j]) + acc[2][nj][r];
      float go = __bfloat162float(G[grow + 3 * 256 + j]) + acc[3][nj][r];
      float cp = (s > 0) ? cs[(size_t)bi * 256 + j] : 0.0f;
      float cn = sigm(gf) * cp + sigm(gi) * tanh_(gg);
      float hn = sigm(go) * tanh_(cn);
      cs[(size_t)bi * 256 + j] = cn;
      hs[(size_t)bi * 256 + j] = __float2bfloat16(hn);
      int bb = bi / 28, rr = bi - bb * 28;
      // out row: vertical stage -> (b, t=w, rr=h); horizontal -> (b, t=h, rr=w).
      outb[(((size_t)bb * 784) + (size_t)t * 28 + rr) * 512 + dir * 256 + j] =
          __float2bfloat16(hn);
    }
  }
}

// ---- K3: row softmax over first 100 cols of P, scatter into W_scr[b][p][k]
// (faithful torch C-order reshape: flat m = o*784+q maps to p=m/100, k=m%100)
__global__ void softmax_scatter(const float* __restrict__ P, bf16_t* __restrict__ Wscr) {
  int row = blockIdx.x;  // (b,h,w) = b*784+q
  int l = threadIdx.x;   // 64
  int b = row / 784, q = row - b * 784;
  const float* pr = P + (size_t)row * 128;
  float v0 = (l < 100) ? pr[l] : -1e30f;
  float v1 = (l + 64 < 100) ? pr[l + 64] : -1e30f;
  float m = fmaxf(v0, v1);
  for (int off = 32; off > 0; off >>= 1) m = fmaxf(m, __shfl_down(m, off));
  m = __shfl(m, 0);
  float e0 = (l < 100) ? __expf(v0 - m) : 0.0f;
  float e1 = (l + 64 < 100) ? __expf(v1 - m) : 0.0f;
  float sum = e0 + e1;
  for (int off = 32; off > 0; off >>= 1) sum += __shfl_down(sum, off);
  sum = __shfl(sum, 0);
  float inv = 1.0f / sum;
  size_t base = (size_t)b * 784 * 128;
  if (l < 100) {
    int mm = l * 784 + q;
    Wscr[base + (size_t)(mm / 100) * 128 + (mm % 100)] = __float2bfloat16(e0 * inv);
  }
  int o = l + 64;
  if (o < 100) {
    int mm = o * 784 + q;
    Wscr[base + (size_t)(mm / 100) * 128 + (mm % 100)] = __float2bfloat16(e1 * inv);
  }
}

// ---- K4: per-b GEMM out[p,c] = sum_k Wscr[b][p][k] * xs[b][c][k]  (K=128 padded;
// Wscr pad cols finite garbage, xs pad cols explicit zeros -> product 0). Output fp32.
__global__ __launch_bounds__(256) void final_gemm(const bf16_t* __restrict__ Wscr,
                                                  const bf16_t* __restrict__ xs,
                                                  float* __restrict__ outp) {
  int m0 = blockIdx.x * 112, n0 = blockIdx.y * 128, b = blockIdx.z;
  int tid = threadIdx.x, w = tid >> 6, l = tid & 63, lm = l & 15, lq = l >> 4;
  const short* Ab = (const short*)Wscr + (size_t)b * 784 * 128;
  const short* Bb = (const short*)xs + (size_t)b * 512 * 128;
  f32x4 acc[7][2] = {};
#pragma unroll
  for (int kk = 0; kk < 4; kk++) {
    short8 b0 = *(const short8*)&Bb[(size_t)(n0 + w * 32 + lm) * 128 + kk * 32 + lq * 8];
    short8 b1 = *(const short8*)&Bb[(size_t)(n0 + w * 32 + 16 + lm) * 128 + kk * 32 + lq * 8];
#pragma unroll
    for (int mi = 0; mi < 7; mi++) {
      short8 a = *(const short8*)&Ab[(size_t)(m0 + mi * 16 + lm) * 128 + kk * 32 + lq * 8];
      acc[mi][0] = MFMA16(a, b0, acc[mi][0]);
      acc[mi][1] = MFMA16(a, b1, acc[mi][1]);
    }
  }
#pragma unroll
  for (int mi = 0; mi < 7; mi++)
#pragma unroll
    for (int ni = 0; ni < 2; ni++) {
      int c = n0 + w * 32 + ni * 16 + lm;
#pragma unroll
      for (int r = 0; r < 4; r++) {
        int p = m0 + mi * 16 + lq * 4 + r;
        outp[(size_t)b * 401408 + (size_t)p * 512 + c] = acc[mi][ni][r];
      }
    }
}

extern "C" void kernel_launch(void* const* d_in, const int* in_sizes, int n_in,
                              void* d_out, int out_size, void* d_ws, size_t ws_size,
                              hipStream_t stream) {
  const float* x = (const float*)d_in[0];
  const float* v_wih_f = (const float*)d_in[1];
  const float* v_whh_f = (const float*)d_in[2];
  const float* v_b_f = (const float*)d_in[3];
  const float* v_wih_b = (const float*)d_in[4];
  const float* v_whh_b = (const float*)d_in[5];
  const float* v_b_b = (const float*)d_in[6];
  const float* h_wih_f = (const float*)d_in[7];
  const float* h_whh_f = (const float*)d_in[8];
  const float* h_b_f = (const float*)d_in[9];
  const float* h_wih_b = (const float*)d_in[10];
  const float* h_whh_b = (const float*)d_in[11];
  const float* h_b_b = (const float*)d_in[12];
  const float* conv_w = (const float*)d_in[13];
  const float* conv_b = (const float*)d_in[14];

  // workspace carve (~313 MB): P/Wscr alias G (G dead by then)
  char* ws = (char*)d_ws;
  bf16_t* Xin = (bf16_t*)(ws);                  // 51,380,224 B (aliased as Hout later)
  bf16_t* Vout = (bf16_t*)(ws + 51380224);      // 51,380,224
  bf16_t* G = (bf16_t*)(ws + 102760448);        // 205,520,896
  float* P = (float*)(ws + 102760448);          // 25,690,112 (alias of G)
  bf16_t* Wscr = (bf16_t*)(ws + 128450560);     // 12,845,056 (alias of G)
  bf16_t* xs = (bf16_t*)(ws + 308281344);       // 8,388,608
  bf16_t* cwp = (bf16_t*)(ws + 316669952);      // 131,072
  float* cbp = (float*)(ws + 316801024);        // 512
  bf16_t* hstate = (bf16_t*)(ws + 316801536);   // 1,835,008
  float* cstate = (float*)(ws + 318636544);     // 3,670,016
  bf16_t* wvf = (bf16_t*)(ws + 322306560);      // v_wih_f bf16: 1,048,576
  bf16_t* wvb = (bf16_t*)(ws + 323355136);      // v_wih_b bf16: 1,048,576
  bf16_t* uvf = (bf16_t*)(ws + 324403712);      // v_whh_f bf16: 524,288
  bf16_t* uvb = (bf16_t*)(ws + 324928000);      // v_whh_b bf16: 524,288
  bf16_t* whf = (bf16_t*)(ws + 325452288);      // h_wih_f bf16: 1,048,576
  bf16_t* whb = (bf16_t*)(ws + 326500864);      // h_wih_b bf16: 1,048,576
  bf16_t* uhf = (bf16_t*)(ws + 327549440);      // h_whh_f bf16: 524,288
  bf16_t* uhb = (bf16_t*)(ws + 328073728);      // h_whh_b bf16: 524,288
  bf16_t* Hout = Xin;

  // weight conversions (fp32 -> bf16)
  cvt_f2b<<<2048, 256, 0, stream>>>(v_wih_f, wvf, 524288);
  cvt_f2b<<<2048, 256, 0, stream>>>(v_wih_b, wvb, 524288);
  cvt_f2b<<<1024, 256, 0, stream>>>(v_whh_f, uvf, 262144);
  cvt_f2b<<<1024, 256, 0, stream>>>(v_whh_b, uvb, 262144);
  cvt_f2b<<<2048, 256, 0, stream>>>(h_wih_f, whf, 524288);
  cvt_f2b<<<2048, 256, 0, stream>>>(h_wih_b, whb, 524288);
  cvt_f2b<<<1024, 256, 0, stream>>>(h_whh_f, uhf, 262144);
  cvt_f2b<<<1024, 256, 0, stream>>>(h_whh_b, uhb, 262144);

  transpose_x<<<dim3(4, 28, 64), 256, 0, stream>>>(x, Xin);
  build_xs<<<dim3(512, 64), 128, 0, stream>>>(x, xs);
  pad_conv<<<dim3(128), 128, 0, stream>>>(conv_w, conv_b, cwp, cbp);

  // vertical stage: G = Xin @ [Wf;Wb]^T + [bf;bb]; then 28 scan steps
  gemm_bt<bf16_t><<<dim3(392, 16), 256, 0, stream>>>(
      Xin, wvf, wvb, 1024, v_b_f, v_b_b, G, NROW, 2048, 512);
  for (int s = 0; s < 28; s++)
    lstm_step<<<dim3(112, 2), 256, 0, stream>>>(G, uvf, uvb, hstate, cstate, Vout, s);

  // horizontal stage
  gemm_bt<bf16_t><<<dim3(392, 16), 256, 0, stream>>>(
      Vout, whf, whb, 1024, h_b_f, h_b_b, G, NROW, 2048, 512);
  for (int s = 0; s < 28; s++)
    lstm_step<<<dim3(112, 2), 256, 0, stream>>>(G, uhf, uhb, hstate, cstate, Hout, s);

  // 1x1 conv (N padded 100->128), softmax+scatter, final attention GEMM
  gemm_bt<float><<<dim3(392, 1), 256, 0, stream>>>(
      Hout, cwp, cwp, 1024, cbp, cbp, P, NROW, 128, 512);
  softmax_scatter<<<dim3(50176), 64, 0, stream>>>(P, Wscr);
  final_gemm<<<dim3(7, 4, 64), 256, 0, stream>>>(Wscr, xs, (float*)d_out);
}

// Round 4
// 1373.518 us; speedup vs baseline: 1.4554x; 1.4554x over previous
//
#include <hip/hip_runtime.h>
#include <hip/hip_bf16.h>
#include <stdint.h>

typedef __hip_bfloat16 bf16_t;
typedef __attribute__((ext_vector_type(8))) short short8;
typedef __attribute__((ext_vector_type(4))) float f32x4;

#define MFMA16(a, b, c) __builtin_amdgcn_mfma_f32_16x16x32_bf16(a, b, c, 0, 0, 0)

#define NROW 50176   // B*S*S
#define NBATCH 1792  // B*S

__device__ __forceinline__ void g2l16(const void* g, void* l) {
  __builtin_amdgcn_global_load_lds(
      (const __attribute__((address_space(1))) unsigned int*)g,
      (__attribute__((address_space(3))) unsigned int*)l, 16, 0, 0);
}
__device__ __forceinline__ float sigm(float x) { return 1.0f / (1.0f + __expf(-x)); }
__device__ __forceinline__ float tanh_(float x) { return 2.0f / (1.0f + __expf(-2.0f * x)) - 1.0f; }
__device__ __forceinline__ void stc(bf16_t* p, float v) { *p = __float2bfloat16(v); }
__device__ __forceinline__ void stc(float* p, float v) { *p = v; }

// ---- fp32 -> bf16 conversion of all 8 LSTM weight matrices in one launch
struct CvtArgs {
  const float* src[8];
  bf16_t* dst[8];
  int n[8];
};
__global__ void cvt_all(CvtArgs a) {
  int arr = blockIdx.y;
  int i = blockIdx.x * 256 + threadIdx.x;
  if (i < a.n[arr]) a.dst[arr][i] = __float2bfloat16(a.src[arr][i]);
}

// ---- K0a: x fp32 [B,512,28,28] -> Xin [(b,h,w), 512] bf16
__global__ void transpose_x(const float* __restrict__ x, bf16_t* __restrict__ Xin) {
  int c0 = blockIdx.x * 128, h = blockIdx.y, b = blockIdx.z;
  __shared__ __align__(16) short tile[128 * 29];
  const float* xb = x + ((size_t)b * 512 + c0) * 784 + h * 28;
  for (int e = threadIdx.x; e < 128 * 28; e += 256) {
    int cc = e / 28, w = e - cc * 28;
    tile[cc * 29 + w] = __bfloat16_as_short(__float2bfloat16(xb[(size_t)cc * 784 + w]));
  }
  __syncthreads();
  short* outb = (short*)Xin + ((size_t)(b * 28 + h) * 28) * 512 + c0;
  for (int e = threadIdx.x; e < 28 * 128; e += 256) {
    int w = e >> 7, cc = e & 127;
    outb[(size_t)w * 512 + cc] = tile[cc * 29 + w];
  }
}

// ---- K0b: x_s[b][c][k<128] = x[b][c][3kh][3kw] (k<100), 0 pad (k>=100), bf16
__global__ void build_xs(const float* __restrict__ x, bf16_t* __restrict__ xs) {
  int c = blockIdx.x, b = blockIdx.y;
  int k = threadIdx.x;  // 128
  const float* xr = x + ((size_t)b * 512 + c) * 784;
  float v = 0.0f;
  if (k < 100) { int kh = k / 10, kw = k - kh * 10; v = xr[kh * 84 + kw * 3]; }
  xs[((size_t)b * 512 + c) * 128 + k] = __float2bfloat16(v);
}

// ---- K0c: pad conv_w fp32 [100,512] -> bf16 [128,512]; conv_b fp32 [100] -> fp32 [128]
__global__ void pad_conv(const float* __restrict__ cw, const float* __restrict__ cb,
                         bf16_t* __restrict__ cwp, float* __restrict__ cbp) {
  int r = blockIdx.x;  // 128
  for (int i = threadIdx.x; i < 512; i += 128)
    cwp[r * 512 + i] = __float2bfloat16((r < 100) ? cw[r * 512 + i] : 0.0f);
  if (r == 0) cbp[threadIdx.x] = (threadIdx.x < 100) ? cb[threadIdx.x] : 0.0f;
}

// ---- K1: C[M,N] = A[M,K] @ Bsel[N,K]^T + bias (m97-style global_load_lds staging)
template <typename CT>
__global__ __launch_bounds__(256) void gemm_bt(
    const bf16_t* __restrict__ A, const bf16_t* __restrict__ B0,
    const bf16_t* __restrict__ B1, int nsplit, const float* __restrict__ bias0,
    const float* __restrict__ bias1, CT* __restrict__ C, int M, int N, int K) {
  __shared__ __align__(16) short As[128 * 32];
  __shared__ __align__(16) short Bs[128 * 32];
  int tid = threadIdx.x;
  int bm0 = blockIdx.x * 128, bn0 = blockIdx.y * 128;
  const bf16_t* Bp;
  const float* biasp;
  if (bn0 < nsplit) { Bp = B0 + (size_t)bn0 * K; biasp = bias0 + bn0; }
  else { Bp = B1 + (size_t)(bn0 - nsplit) * K; biasp = bias1 + (bn0 - nsplit); }
  int lrow = tid >> 2, lseg = tid & 3;  // 4 threads x 16B cover one 32-elem row
  const char* Ag = (const char*)(A + (size_t)(bm0 + lrow) * K) + lseg * 16;
  const char* Bg = (const char*)(Bp + (size_t)lrow * K) + lseg * 16;
  size_t radv = (size_t)64 * K * 2;  // 64 rows down
  int w = tid >> 6, l = tid & 63, lm = l & 15, lq = l >> 4;
  int wm = w & 1, wn = w >> 1;
  f32x4 acc[4][4] = {};
  for (int k0 = 0; k0 < K; k0 += 32) {
    g2l16(Ag, (char*)As + tid * 16);
    g2l16(Ag + radv, (char*)As + 4096 + tid * 16);
    g2l16(Bg, (char*)Bs + tid * 16);
    g2l16(Bg + radv, (char*)Bs + 4096 + tid * 16);
    Ag += 64; Bg += 64;
    __syncthreads();
    short8 afr[4], bfr[4];
#pragma unroll
    for (int i = 0; i < 4; i++) {
      afr[i] = *(const short8*)&As[(wm * 64 + i * 16 + lm) * 32 + lq * 8];
      bfr[i] = *(const short8*)&Bs[(wn * 64 + i * 16 + lm) * 32 + lq * 8];
    }
#pragma unroll
    for (int mi = 0; mi < 4; mi++)
#pragma unroll
      for (int ni = 0; ni < 4; ni++) acc[mi][ni] = MFMA16(afr[mi], bfr[ni], acc[mi][ni]);
    __syncthreads();
  }
  float bv[4];
#pragma unroll
  for (int ni = 0; ni < 4; ni++) bv[ni] = biasp[wn * 64 + ni * 16 + lm];
#pragma unroll
  for (int mi = 0; mi < 4; mi++)
#pragma unroll
    for (int ni = 0; ni < 4; ni++) {
      int col = bn0 + wn * 64 + ni * 16 + lm;
#pragma unroll
      for (int r = 0; r < 4; r++) {
        size_t row = bm0 + wm * 64 + mi * 16 + lq * 4 + r;
        stc(&C[row * N + col], acc[mi][ni][r] + bv[ni]);
      }
    }
}

// ---- K2: one LSTM step, both directions. Block = (dir, js: 32 hidden cols, rg: 64 rows).
// whh slice (4 gates x 32 cols = 128 rows x 256 K = 64 KB) staged in LDS once, XOR-swizzled
// 16B granules so b-fragment ds_reads are conflict-free. i,f,g,o for (row,j) land in the
// same lane's accumulators -> pure-register gate epilogue.
__global__ __launch_bounds__(256) void lstm_step(
    const bf16_t* __restrict__ G, const bf16_t* __restrict__ whh_f,
    const bf16_t* __restrict__ whh_b, bf16_t* __restrict__ hstate,
    float* __restrict__ cstate, bf16_t* __restrict__ outb, int s) {
  int dir = blockIdx.y;
  int t = dir ? 27 - s : s;
  int js = blockIdx.x & 7;   // 32-col hidden slice
  int rg = blockIdx.x >> 3;  // 0..27, 64 rows each
  int tid = threadIdx.x, w = tid >> 6, l = tid & 63, lm = l & 15, lq = l >> 4;
  const short* whh = (const short*)(dir ? whh_b : whh_f);
  bf16_t* hs = hstate + (size_t)dir * NBATCH * 256;
  float* cs = cstate + (size_t)dir * NBATCH * 256;
  __shared__ __align__(16) short Ws[128 * 256];  // 64 KB, swizzled
#pragma unroll
  for (int i = 0; i < 16; i++) {
    int segid = i * 256 + tid;  // < 4096
    int row = segid >> 5, seg = segid & 31;
    int gate = row >> 5, jj = row & 31;
    short8 v = *(const short8*)&whh[((size_t)(gate * 256 + js * 32 + jj)) * 256 + seg * 8];
    *(short8*)&Ws[row * 256 + ((seg ^ (row & 7)) * 8)] = v;
  }
  __syncthreads();
  int r0 = rg * 64 + w * 16;  // wave's 16 batch rows
  f32x4 acc[4][2] = {};
  if (s > 0) {
    const short* hp = (const short*)hs;
#pragma unroll
    for (int kk = 0; kk < 8; kk++) {
      short8 a = *(const short8*)&hp[(size_t)(r0 + lm) * 256 + kk * 32 + lq * 8];
      int bseg = ((kk * 4 + lq) ^ (lm & 7)) * 8;
#pragma unroll
      for (int gate = 0; gate < 4; gate++)
#pragma unroll
        for (int nj = 0; nj < 2; nj++) {
          short8 b = *(const short8*)&Ws[(gate * 32 + nj * 16 + lm) * 256 + bseg];
          acc[gate][nj] = MFMA16(a, b, acc[gate][nj]);
        }
    }
  }
#pragma unroll
  for (int nj = 0; nj < 2; nj++) {
    int j = js * 32 + nj * 16 + lm;
#pragma unroll
    for (int r = 0; r < 4; r++) {
      int bi = r0 + lq * 4 + r;
      size_t grow = ((size_t)bi * 28 + t) * 2048 + (size_t)dir * 1024;
      float gi = __bfloat162float(G[grow + 0 * 256 + j]) + acc[0][nj][r];
      float gf = __bfloat162float(G[grow + 1 * 256 + j]) + acc[1][nj][r];
      float gg = __bfloat162float(G[grow + 2 * 256 + j]) + acc[2][nj][r];
      float go = __bfloat162float(G[grow + 3 * 256 + j]) + acc[3][nj][r];
      float cp = (s > 0) ? cs[(size_t)bi * 256 + j] : 0.0f;
      float cn = sigm(gf) * cp + sigm(gi) * tanh_(gg);
      float hn = sigm(go) * tanh_(cn);
      cs[(size_t)bi * 256 + j] = cn;
      hs[(size_t)bi * 256 + j] = __float2bfloat16(hn);
      int bb = bi / 28, rr = bi - bb * 28;
      // out row: vertical stage -> (b, t=w, rr=h); horizontal -> (b, t=h, rr=w).
      outb[(((size_t)bb * 784) + (size_t)t * 28 + rr) * 512 + dir * 256 + j] =
          __float2bfloat16(hn);
    }
  }
}

// ---- K3: row softmax over first 100 cols of P, scatter into W_scr[b][p][k]
// (faithful torch C-order reshape: flat m = o*784+q maps to p=m/100, k=m%100)
__global__ void softmax_scatter(const float* __restrict__ P, bf16_t* __restrict__ Wscr) {
  int row = blockIdx.x;  // (b,h,w) = b*784+q
  int l = threadIdx.x;   // 64
  int b = row / 784, q = row - b * 784;
  const float* pr = P + (size_t)row * 128;
  float v0 = (l < 100) ? pr[l] : -1e30f;
  float v1 = (l + 64 < 100) ? pr[l + 64] : -1e30f;
  float m = fmaxf(v0, v1);
  for (int off = 32; off > 0; off >>= 1) m = fmaxf(m, __shfl_down(m, off));
  m = __shfl(m, 0);
  float e0 = (l < 100) ? __expf(v0 - m) : 0.0f;
  float e1 = (l + 64 < 100) ? __expf(v1 - m) : 0.0f;
  float sum = e0 + e1;
  for (int off = 32; off > 0; off >>= 1) sum += __shfl_down(sum, off);
  sum = __shfl(sum, 0);
  float inv = 1.0f / sum;
  size_t base = (size_t)b * 784 * 128;
  if (l < 100) {
    int mm = l * 784 + q;
    Wscr[base + (size_t)(mm / 100) * 128 + (mm % 100)] = __float2bfloat16(e0 * inv);
  }
  int o = l + 64;
  if (o < 100) {
    int mm = o * 784 + q;
    Wscr[base + (size_t)(mm / 100) * 128 + (mm % 100)] = __float2bfloat16(e1 * inv);
  }
}

// ---- K4: per-b GEMM out[p,c] = sum_k Wscr[b][p][k] * xs[b][c][k]  (K=128 padded;
// Wscr pad cols finite garbage, xs pad cols explicit zeros -> product 0). Output fp32.
__global__ __launch_bounds__(256) void final_gemm(const bf16_t* __restrict__ Wscr,
                                                  const bf16_t* __restrict__ xs,
                                                  float* __restrict__ outp) {
  int m0 = blockIdx.x * 112, n0 = blockIdx.y * 128, b = blockIdx.z;
  int tid = threadIdx.x, w = tid >> 6, l = tid & 63, lm = l & 15, lq = l >> 4;
  const short* Ab = (const short*)Wscr + (size_t)b * 784 * 128;
  const short* Bb = (const short*)xs + (size_t)b * 512 * 128;
  f32x4 acc[7][2] = {};
#pragma unroll
  for (int kk = 0; kk < 4; kk++) {
    short8 b0 = *(const short8*)&Bb[(size_t)(n0 + w * 32 + lm) * 128 + kk * 32 + lq * 8];
    short8 b1 = *(const short8*)&Bb[(size_t)(n0 + w * 32 + 16 + lm) * 128 + kk * 32 + lq * 8];
#pragma unroll
    for (int mi = 0; mi < 7; mi++) {
      short8 a = *(const short8*)&Ab[(size_t)(m0 + mi * 16 + lm) * 128 + kk * 32 + lq * 8];
      acc[mi][0] = MFMA16(a, b0, acc[mi][0]);
      acc[mi][1] = MFMA16(a, b1, acc[mi][1]);
    }
  }
#pragma unroll
  for (int mi = 0; mi < 7; mi++)
#pragma unroll
    for (int ni = 0; ni < 2; ni++) {
      int c = n0 + w * 32 + ni * 16 + lm;
#pragma unroll
      for (int r = 0; r < 4; r++) {
        int p = m0 + mi * 16 + lq * 4 + r;
        outp[(size_t)b * 401408 + (size_t)p * 512 + c] = acc[mi][ni][r];
      }
    }
}

extern "C" void kernel_launch(void* const* d_in, const int* in_sizes, int n_in,
                              void* d_out, int out_size, void* d_ws, size_t ws_size,
                              hipStream_t stream) {
  const float* x = (const float*)d_in[0];
  const float* v_wih_f = (const float*)d_in[1];
  const float* v_whh_f = (const float*)d_in[2];
  const float* v_b_f = (const float*)d_in[3];
  const float* v_wih_b = (const float*)d_in[4];
  const float* v_whh_b = (const float*)d_in[5];
  const float* v_b_b = (const float*)d_in[6];
  const float* h_wih_f = (const float*)d_in[7];
  const float* h_whh_f = (const float*)d_in[8];
  const float* h_b_f = (const float*)d_in[9];
  const float* h_wih_b = (const float*)d_in[10];
  const float* h_whh_b = (const float*)d_in[11];
  const float* h_b_b = (const float*)d_in[12];
  const float* conv_w = (const float*)d_in[13];
  const float* conv_b = (const float*)d_in[14];

  // workspace carve (~329 MB): P/Wscr alias G (G dead by then)
  char* ws = (char*)d_ws;
  bf16_t* Xin = (bf16_t*)(ws);                  // 51,380,224 B (aliased as Hout later)
  bf16_t* Vout = (bf16_t*)(ws + 51380224);      // 51,380,224
  bf16_t* G = (bf16_t*)(ws + 102760448);        // 205,520,896
  float* P = (float*)(ws + 102760448);          // 25,690,112 (alias of G)
  bf16_t* Wscr = (bf16_t*)(ws + 128450560);     // 12,845,056 (alias of G)
  bf16_t* xs = (bf16_t*)(ws + 308281344);       // 8,388,608
  bf16_t* cwp = (bf16_t*)(ws + 316669952);      // 131,072
  float* cbp = (float*)(ws + 316801024);        // 512
  bf16_t* hstate = (bf16_t*)(ws + 316801536);   // 1,835,008
  float* cstate = (float*)(ws + 318636544);     // 3,670,016
  bf16_t* wvf = (bf16_t*)(ws + 322306560);      // v_wih_f bf16: 1,048,576
  bf16_t* wvb = (bf16_t*)(ws + 323355136);      // v_wih_b bf16: 1,048,576
  bf16_t* uvf = (bf16_t*)(ws + 324403712);      // v_whh_f bf16: 524,288
  bf16_t* uvb = (bf16_t*)(ws + 324928000);      // v_whh_b bf16: 524,288
  bf16_t* whf = (bf16_t*)(ws + 325452288);      // h_wih_f bf16: 1,048,576
  bf16_t* whb = (bf16_t*)(ws + 326500864);      // h_wih_b bf16: 1,048,576
  bf16_t* uhf = (bf16_t*)(ws + 327549440);      // h_whh_f bf16: 524,288
  bf16_t* uhb = (bf16_t*)(ws + 328073728);      // h_whh_b bf16: 524,288
  bf16_t* Hout = Xin;

  CvtArgs ca;
  ca.src[0] = v_wih_f; ca.dst[0] = wvf; ca.n[0] = 524288;
  ca.src[1] = v_wih_b; ca.dst[1] = wvb; ca.n[1] = 524288;
  ca.src[2] = v_whh_f; ca.dst[2] = uvf; ca.n[2] = 262144;
  ca.src[3] = v_whh_b; ca.dst[3] = uvb; ca.n[3] = 262144;
  ca.src[4] = h_wih_f; ca.dst[4] = whf; ca.n[4] = 524288;
  ca.src[5] = h_wih_b; ca.dst[5] = whb; ca.n[5] = 524288;
  ca.src[6] = h_whh_f; ca.dst[6] = uhf; ca.n[6] = 262144;
  ca.src[7] = h_whh_b; ca.dst[7] = uhb; ca.n[7] = 262144;
  cvt_all<<<dim3(2048, 8), 256, 0, stream>>>(ca);

  transpose_x<<<dim3(4, 28, 64), 256, 0, stream>>>(x, Xin);
  build_xs<<<dim3(512, 64), 128, 0, stream>>>(x, xs);
  pad_conv<<<dim3(128), 128, 0, stream>>>(conv_w, conv_b, cwp, cbp);

  // vertical stage: G = Xin @ [Wf;Wb]^T + [bf;bb]; then 28 scan steps
  gemm_bt<bf16_t><<<dim3(392, 16), 256, 0, stream>>>(
      Xin, wvf, wvb, 1024, v_b_f, v_b_b, G, NROW, 2048, 512);
  for (int s = 0; s < 28; s++)
    lstm_step<<<dim3(224, 2), 256, 0, stream>>>(G, uvf, uvb, hstate, cstate, Vout, s);

  // horizontal stage
  gemm_bt<bf16_t><<<dim3(392, 16), 256, 0, stream>>>(
      Vout, whf, whb, 1024, h_b_f, h_b_b, G, NROW, 2048, 512);
  for (int s = 0; s < 28; s++)
    lstm_step<<<dim3(224, 2), 256, 0, stream>>>(G, uhf, uhb, hstate, cstate, Hout, s);

  // 1x1 conv (N padded 100->128), softmax+scatter, final attention GEMM
  gemm_bt<float><<<dim3(392, 1), 256, 0, stream>>>(
      Hout, cwp, cwp, 1024, cbp, cbp, P, NROW, 128, 512);
  softmax_scatter<<<dim3(50176), 64, 0, stream>>>(P, Wscr);
  final_gemm<<<dim3(7, 4, 64), 256, 0, stream>>>(Wscr, xs, (float*)d_out);
}